// Round 8
// baseline (50.861 us; speedup 1.0000x reference)
//
#include <hip/hip_runtime.h>

#define N_IN 59
#define N_VALUES 12
#define BLOCK 256
#define WROWS 16                        // rows per tile (one 16x16 MFMA)
#define TILE_F (WROWS * N_IN)           // 944 floats per tile
#define TILE_BYTES (TILE_F * 4)         // 3776 B
#define BUF_STRIDE_F 952                // +8 pad words (zeroed once)
#define FV_STRIDE 12                    // fv [16][12] per wave
#define WL_STRIDE 68                    // padded W image row stride (words)
#define WL_FLOATS (16 * WL_STRIDE)      // 1088 words
#define GRID 1024                       // 4 blocks/CU exactly (LDS: 34816 B)
#define WAVES 4
#define NWAVES (GRID * WAVES)           // 4096 waves
#define NT 62500                        // 1e6 / 16 tiles

typedef __attribute__((ext_vector_type(4))) float  f32x4;
typedef __attribute__((ext_vector_type(8))) __bf16 bf16x8;

// async-stage one 944-float tile into wave-private LDS (linear dest:
// wave-uniform base + lane*16). 3 full wave-wide DMAs + 44 lanes on the 4th;
// always 4 vmcnt events per wave (exec!=0 on the predicated one).
static __device__ __forceinline__ void stage_tile(const float* act, int tt,
                                                  int lane, float* dst) {
    const char* s = (const char*)act + (long)tt * TILE_BYTES + lane * 16;
    char* d = (char*)dst;
    __builtin_amdgcn_global_load_lds(
        (const __attribute__((address_space(1))) void*)(s),
        (__attribute__((address_space(3))) void*)(d), 16, 0, 0);
    __builtin_amdgcn_global_load_lds(
        (const __attribute__((address_space(1))) void*)(s + 1024),
        (__attribute__((address_space(3))) void*)(d + 1024), 16, 0, 0);
    __builtin_amdgcn_global_load_lds(
        (const __attribute__((address_space(1))) void*)(s + 2048),
        (__attribute__((address_space(3))) void*)(d + 2048), 16, 0, 0);
    if (lane < 44) {
        __builtin_amdgcn_global_load_lds(
            (const __attribute__((address_space(1))) void*)(s + 3072),
            (__attribute__((address_space(3))) void*)(d + 3072), 16, 0, 0);
    }
}

__global__ __launch_bounds__(BLOCK, 4) void value_model_kernel(
    const float* __restrict__ act,      // [B, 59]
    const int*   __restrict__ cards,    // [B, 4, 3] int32
    const float* __restrict__ W,        // [12, 59]
    const float* __restrict__ bias,     // [12]
    float* __restrict__ out)            // [B, 4]
{
    // 4 waves x 2 buffers x 952 words + 1088-word W-image/fv union = 34816 B.
    __shared__ float aLds[WAVES * 2 * BUF_STRIDE_F];
    __shared__ float xLds[WL_FLOATS];   // setup: padded W image; steady: fv

    const int tid  = threadIdx.x;
    const int wave = tid >> 6;
    const int lane = tid & 63;
    float* buf0 = aLds + wave * (2 * BUF_STRIDE_F);
    float* buf1 = buf0 + BUF_STRIDE_F;

    // ---- one-time setup (lgkm fences + s_barrier only; vmcnt untouched) ----
    for (int i = tid; i < WL_FLOATS; i += BLOCK) xLds[i] = 0.0f;  // zero W image
    if (lane < BUF_STRIDE_F - TILE_F) {                           // zero act pads
        buf0[TILE_F + lane] = 0.0f;
        buf1[TILE_F + lane] = 0.0f;
    }
    asm volatile("s_waitcnt lgkmcnt(0)" ::: "memory");
    __builtin_amdgcn_s_barrier();

    for (int i = tid; i < N_VALUES * N_IN; i += BLOCK) {          // scatter W
        int v = i / N_IN;
        int j = i - v * N_IN;
        xLds[v * WL_STRIDE + j] = W[i];
    }
    asm volatile("s_waitcnt lgkmcnt(0)" ::: "memory");
    __builtin_amdgcn_s_barrier();

    // B-fragments: lane l holds B[k=(l>>4)*8+e][col=l&15], K-half h; zero-padded.
    const int colA = lane & 15, gA = lane >> 4;
    bf16x8 bf0, bf1;
    {
        const float* wp = xLds + colA * WL_STRIDE + gA * 8;
        #pragma unroll
        for (int e = 0; e < 8; ++e) bf0[e] = (__bf16)wp[e];
        #pragma unroll
        for (int e = 0; e < 8; ++e) bf1[e] = (__bf16)wp[32 + e];
    }
    float bv = 0.0f;
    if (colA < N_VALUES) bv = bias[colA];
    asm volatile("s_waitcnt lgkmcnt(0)" ::: "memory");
    __builtin_amdgcn_s_barrier();       // xLds now reusable as fv

    float* fw = xLds + wave * (WROWS * FV_STRIDE);
    const int r4 = lane >> 2, c4 = lane & 3;

    // ---- persistent 2-deep pipeline over tiles wid, wid+4096, ... ----------
    int t = blockIdx.x * WAVES + wave;  // first tile for this wave (< 4096)
    int ca, cb, cc;
    {   // prologue: cards(t0) then stage(t0) -> buf0
        const int* cp = cards + ((long)t * WROWS + r4) * 12 + c4 * 3;
        ca = cp[0]; cb = cp[1]; cc = cp[2];
        stage_tile(act, t, lane, buf0);
    }
    int cur = 0;
    while (t < NT) {
        const int nxt = t + NWAVES;
        const bool hasNext = nxt < NT;  // wave-uniform

        // issue next tile's loads FIRST (cards before stage: keeps the
        // counted wait below exact under in-order vmcnt retirement)
        int na = 0, nb = 0, nc2 = 0;
        if (hasNext) {
            const int* cp = cards + ((long)nxt * WROWS + r4) * 12 + c4 * 3;
            na = cp[0]; nb = cp[1]; nc2 = cp[2];
            stage_tile(act, nxt, lane, cur ? buf0 : buf1);
        }

        // wait for stage(t) only: 8 vm-ops issued after its last DMA in steady
        // state (1 store + 3 cards + 4 DMA); vmcnt completes oldest-first, so
        // vmcnt(7) leaves exactly the next tile's loads in flight.
        if (hasNext) asm volatile("s_waitcnt vmcnt(7)" ::: "memory");
        else         asm volatile("s_waitcnt vmcnt(0)" ::: "memory");
        __builtin_amdgcn_sched_barrier(0);
        __builtin_amdgcn_wave_barrier();

        // A-frags from LDS (word stride 59, odd -> <=2 lanes/bank = free)
        float* tw = cur ? buf1 : buf0;
        const float* p = tw + colA * N_IN + gA * 8;
        bf16x8 a0, a1;
        #pragma unroll
        for (int e = 0; e < 8; ++e) a0[e] = (__bf16)p[e];
        #pragma unroll
        for (int e = 0; e < 8; ++e) a1[e] = (__bf16)p[32 + e];

        f32x4 acc = {bv, bv, bv, bv};
        acc = __builtin_amdgcn_mfma_f32_16x16x32_bf16(a0, bf0, acc, 0, 0, 0);
        acc = __builtin_amdgcn_mfma_f32_16x16x32_bf16(a1, bf1, acc, 0, 0, 0);

        // C[row=(l>>4)*4+j][col=l&15] -> fv [16][12]
        if (colA < N_VALUES) {
            #pragma unroll
            for (int j = 0; j < 4; ++j)
                fw[(gA * 4 + j) * FV_STRIDE + colA] = acc[j];
        }
        asm volatile("s_waitcnt lgkmcnt(0)" ::: "memory");
        __builtin_amdgcn_wave_barrier();

        // gather: 1 card (3 indices) per lane, contiguous dword store
        const float* fv = fw + r4 * FV_STRIDE;
        out[((long)t * WROWS + r4) * 4 + c4] = fv[ca] + fv[cb] + fv[cc];

        ca = na; cb = nb; cc = nc2;
        cur ^= 1;
        t = nxt;
    }
}

extern "C" void kernel_launch(void* const* d_in, const int* in_sizes, int n_in,
                              void* d_out, int out_size, void* d_ws, size_t ws_size,
                              hipStream_t stream) {
    const float* act   = (const float*)d_in[0];
    const int*   cards = (const int*)d_in[1];
    const float* W     = (const float*)d_in[2];
    const float* bias  = (const float*)d_in[3];
    float* out = (float*)d_out;

    value_model_kernel<<<GRID, BLOCK, 0, stream>>>(act, cards, W, bias, out);
}